// Round 5
// baseline (337.414 us; speedup 1.0000x reference)
//
#include <hip/hip_runtime.h>
#include <hip/hip_bf16.h>

// LatentMatrixMemory: M_t = lam*M + (rho*alpha)*(k outer v); r_t = q^T M_t
// B=64, T=2048, DK=DV=128, fp32 in/out. Threshold permits bf16 compute.
//
// Round 7: 2 INDEPENDENT blocks/CU (the round-6 8-wave lockstep regressed:
// barrier-synced waves stall together). Round-3 4-wave split restored.
//  - NSPLIT=8 (j=16/block) -> 512 blocks = 2 blocks/CU; independent blocks
//    drift, so one block's barrier drains / shfl chains overlap the other's
//    issue. __launch_bounds__(256,2).
//  - k tile now bf16 in LDS ([2][64][136] padded, no XOR): per-block LDS
//    ~53 KB so two blocks fit in 160 KB. fp32->bf16 conversion happens in
//    registers (T14 reg-staging: loads issued top of phase B, covered by
//    GEMM3/2/4, cvt+ds_write just before loop-top barrier). GEMM1/GEMM4
//    read bf16 directly (no per-fragment cvt on the chain).
//  - Ratio-form decay (no 1/P), 2 barriers/chunk, q/v/scalars register-
//    prefetched a chunk ahead, XCD-chunked block swizzle (8 splits of a
//    batch share an XCD -> k/q L2-hot).
// Grid: 8 DV-splits x 64 batches = 512 blocks; block = 4 waves.

typedef float  f32x4  __attribute__((ext_vector_type(4)));
typedef short  bf16x8 __attribute__((ext_vector_type(8)));
typedef short  bf16x4 __attribute__((ext_vector_type(4)));

constexpr int B_ = 64, T_ = 2048;
constexpr int NSPLIT = 8;
constexpr int CT = 64;          // chunk length
constexpr int NCH = T_ / CT;    // 32 chunks

__device__ __forceinline__ bf16x8 cvt8(float4 a, float4 b) {
  union { __hip_bfloat162 h2[4]; bf16x8 v; } u;
  u.h2[0] = __float22bfloat162_rn(make_float2(a.x, a.y));
  u.h2[1] = __float22bfloat162_rn(make_float2(a.z, a.w));
  u.h2[2] = __float22bfloat162_rn(make_float2(b.x, b.y));
  u.h2[3] = __float22bfloat162_rn(make_float2(b.z, b.w));
  return u.v;
}

__device__ __forceinline__ float fexp2(float x) { return __builtin_exp2f(x); }
__device__ __forceinline__ float flog2(float x) { return __builtin_log2f(x); }

#define MFMA(a, b, c) __builtin_amdgcn_mfma_f32_16x16x32_bf16((a), (b), (c), 0, 0, 0)

__global__ __launch_bounds__(256, 2) void lmm_2b(
    const float* __restrict__ q_g, const float* __restrict__ k_g,
    const float* __restrict__ v_g, const float* __restrict__ a_g,
    const float* __restrict__ r_g, const float* __restrict__ l_g,
    const float* __restrict__ m0_g, float* __restrict__ out_g)
{
  // XCD-chunked bijective swizzle: bid = [btop(3)|split(3)|xcd(3)].
  const int bid   = blockIdx.y * NSPLIT + blockIdx.x;   // 0..511
  const int b     = (bid & 7) * 8 + (bid >> 6);
  const int split = (bid >> 3) & 7;

  const int tid   = threadIdx.x;
  const int w     = tid >> 6;        // wave 0..3
  const int lane  = tid & 63;
  const int m     = lane & 15;
  const int quad  = lane >> 4;
  const int jbase = split * 16;

  // LDS (bf16). Row strides are multiples of 8 bf16 (16B alignment for b128).
  __shared__ __align__(16) __hip_bfloat16 klds[2][64][136]; // k tile, padded
  __shared__ __align__(16) __hip_bfloat16 MhT [16][136];    // bf16(M)^T [j][i]
  __shared__ __align__(16) __hip_bfloat16 VwT [16][72];     // (ar*v)^T  [j][s]
  __shared__ __align__(16) __hip_bfloat16 VwTd[16][72];     // (ar*ratio*v)^T
  __shared__ __align__(16) __hip_bfloat16 Sd[4][16][72];    // scores [tb][t][s]

  const float* qb = q_g + (size_t)b * T_ * 128;
  const float* kb = k_g + (size_t)b * T_ * 128;
  const float* vb = v_g + (size_t)b * T_ * 128;
  const float* ab = a_g + (size_t)b * T_;
  const float* rb = r_g + (size_t)b * T_;
  const float* lb = l_g + (size_t)b * T_;
  float*       ob = out_g + (size_t)b * T_ * 128;

  // ---- M accumulator: wave w owns i-rows [32w,+32), j-cols [jbase,+16) ----
  f32x4 M[2];
  #pragma unroll
  for (int it = 0; it < 2; ++it)
    #pragma unroll
    for (int r = 0; r < 4; ++r)
      M[it][r] = m0_g[((size_t)b * 128 + w * 32 + it * 16 + quad * 4 + r) * 128 +
                      jbase + m];

  // ---- staging lane mappings ----
  const int jv   = tid & 15;   // V staging column (0..15)
  const int s16  = tid >> 4;   // V staging 4-row s-block (0..15)
  const int krow = tid >> 2;   // k staging row (0..63)
  const int kc4  = tid & 3;    // k staging 32-col quarter

  float4 qpre[4][2];
  float4 kpre[8];
  float  vpre[4];
  float  lpre, apre, rpre;

  // ---- chunk-0 staging: k -> regs -> bf16 LDS; q/v/scalars -> regs ----
  lpre = lb[lane]; apre = ab[lane]; rpre = rb[lane];
  #pragma unroll
  for (int f = 0; f < 8; ++f)
    kpre[f] = *(const float4*)&kb[(size_t)krow * 128 + kc4 * 32 + f * 4];
  #pragma unroll
  for (int ks = 0; ks < 4; ++ks) {
    const float* p = qb + (size_t)(w * 16 + m) * 128 + ks * 32 + quad * 8;
    qpre[ks][0] = *(const float4*)p;
    qpre[ks][1] = *(const float4*)(p + 4);
  }
  #pragma unroll
  for (int rep = 0; rep < 4; ++rep)
    vpre[rep] = vb[(size_t)(s16 * 4 + rep) * 128 + jbase + jv];
  #pragma unroll
  for (int g = 0; g < 4; ++g)
    *(bf16x8*)&klds[0][krow][kc4 * 32 + g * 8] =
        cvt8(kpre[2 * g], kpre[2 * g + 1]);

  #pragma unroll 2
  for (int ch = 0; ch < NCH; ++ch) {
    const int t0   = ch * CT;
    const int tn   = (ch + 1 < NCH) ? t0 + CT : t0;  // clamped prefetch base
    const int buf  = ch & 1;
    const int nbuf = buf ^ 1;

    __syncthreads();  // B1: klds[buf]/prefetched regs valid; WAR on LDS bufs

    // ================= phase A =================
    // decay prefix scan in log2 space (redundant per wave)
    float x = flog2(fmaxf(lpre, 1e-20f));
    #pragma unroll
    for (int d = 1; d < 64; d <<= 1) {
      const float o = __shfl_up(x, d, 64);
      if (lane >= d) x += o;
    }
    const float L2    = x;
    const float L2end = __shfl(L2, 63, 64);
    const float arp   = apre * rpre;

    bf16x8 qf[4];
    #pragma unroll
    for (int ks = 0; ks < 4; ++ks) qf[ks] = cvt8(qpre[ks][0], qpre[ks][1]);

    const int tl0 = w * 16 + quad * 4;
    float tl[4];
    #pragma unroll
    for (int r = 0; r < 4; ++r) tl[r] = __shfl(L2, tl0 + r, 64);

    // GEMM1: own 16 t-rows x all 64 s, k bf16 straight from LDS
    f32x4 S[4] = {{0.f,0.f,0.f,0.f},{0.f,0.f,0.f,0.f},
                  {0.f,0.f,0.f,0.f},{0.f,0.f,0.f,0.f}};
    #pragma unroll
    for (int sb = 0; sb < 4; ++sb) {
      const int rowk = sb * 16 + m;
      #pragma unroll
      for (int ks = 0; ks < 4; ++ks) {
        const bf16x8 kf = *(const bf16x8*)&klds[buf][rowk][ks * 32 + quad * 8];
        S[sb] = MFMA(qf[ks], kf, S[sb]);
      }
    }

    // decay + causal mask -> Sd (wave-private tile)
    #pragma unroll
    for (int sb = 0; sb < 4; ++sb) {
      const int   sl_i = sb * 16 + m;
      const float sl   = __shfl(L2, sl_i, 64);
      #pragma unroll
      for (int r = 0; r < 4; ++r) {
        const float dv = (sl_i <= tl0 + r) ? S[sb][r] * fexp2(tl[r] - sl) : 0.f;
        Sd[w][quad * 4 + r][sl_i] = __float2bfloat16(dv);
      }
    }

    // stage VwT = (ar*v)^T and VwTd = (ar*ratio*v)^T (b64 per lane)
    {
      float fw[4], fd[4];
      #pragma unroll
      for (int rep = 0; rep < 4; ++rep) {
        const int   s   = s16 * 4 + rep;
        const float arf = __shfl(arp, s, 64);
        const float dcf = fexp2(L2end - __shfl(L2, s, 64));   // <= 1
        fw[rep] = vpre[rep] * arf;
        fd[rep] = fw[rep] * dcf;
      }
      union { __hip_bfloat162 h2[2]; bf16x4 v; } uw, ud;
      uw.h2[0] = __float22bfloat162_rn(make_float2(fw[0], fw[1]));
      uw.h2[1] = __float22bfloat162_rn(make_float2(fw[2], fw[3]));
      ud.h2[0] = __float22bfloat162_rn(make_float2(fd[0], fd[1]));
      ud.h2[1] = __float22bfloat162_rn(make_float2(fd[2], fd[3]));
      *(bf16x4*)&VwT [jv][s16 * 4] = uw.v;
      *(bf16x4*)&VwTd[jv][s16 * 4] = ud.v;
    }

    // publish bf16(M)^T: wave w -> i-cols [32w,+32)
    #pragma unroll
    for (int it = 0; it < 2; ++it) {
      union { __hip_bfloat162 h2[2]; uint2 u; } pk;
      pk.h2[0] = __float22bfloat162_rn(make_float2(M[it][0], M[it][1]));
      pk.h2[1] = __float22bfloat162_rn(make_float2(M[it][2], M[it][3]));
      *(uint2*)&MhT[m][w * 32 + it * 16 + quad * 4] = pk.u;
    }

    __syncthreads();  // B2: Sd/VwT/VwTd/MhT visible

    // ================= phase B =================
    // issue next-chunk loads NOW; GEMM3/2/4 provide the cover (T14 split:
    // the k cvt+ds_write lands after the GEMMs, just before B1).
    lpre = lb[tn + lane]; apre = ab[tn + lane]; rpre = rb[tn + lane];
    #pragma unroll
    for (int f = 0; f < 8; ++f)
      kpre[f] = *(const float4*)&kb[(size_t)(tn + krow) * 128 + kc4 * 32 + f * 4];
    #pragma unroll
    for (int ks = 0; ks < 4; ++ks) {
      const float* p = qb + (size_t)(tn + w * 16 + m) * 128 + ks * 32 + quad * 8;
      qpre[ks][0] = *(const float4*)p;
      qpre[ks][1] = *(const float4*)(p + 4);
    }
    #pragma unroll
    for (int rep = 0; rep < 4; ++rep)
      vpre[rep] = vb[(size_t)(tn + s16 * 4 + rep) * 128 + jbase + jv];

    // GEMM3: inter-chunk readout q . bf16(M)
    f32x4 R = {0.f, 0.f, 0.f, 0.f};
    #pragma unroll
    for (int ks = 0; ks < 4; ++ks) {
      const bf16x8 mb = *(const bf16x8*)&MhT[m][ks * 32 + quad * 8];
      R = MFMA(qf[ks], mb, R);
    }
    #pragma unroll
    for (int r = 0; r < 4; ++r) R[r] *= fexp2(tl[r]);   // P_t <= 1

    // GEMM2: intra-chunk (decay folded into Sd)
    #pragma unroll
    for (int kk = 0; kk < 2; ++kk) {
      const bf16x8 sa = *(const bf16x8*)&Sd[w][m][kk * 32 + quad * 8];
      const bf16x8 vw = *(const bf16x8*)&VwT[m][kk * 32 + quad * 8];
      R = MFMA(sa, vw, R);
    }
    #pragma unroll
    for (int r = 0; r < 4; ++r)
      ob[(size_t)(t0 + w * 16 + quad * 4 + r) * 128 + jbase + m] = R[r];

    // GEMM4: M = exp2(L2_end)*M + K^T (ar*ratio*v); k bf16 gather from LDS
    const float eend = fexp2(L2end);
    #pragma unroll
    for (int it = 0; it < 2; ++it)
      #pragma unroll
      for (int r = 0; r < 4; ++r) M[it][r] *= eend;
    #pragma unroll
    for (int kk = 0; kk < 2; ++kk) {
      const bf16x8 vd = *(const bf16x8*)&VwTd[m][kk * 32 + quad * 8];
      #pragma unroll
      for (int it = 0; it < 2; ++it) {
        union { __hip_bfloat16 h[8]; bf16x8 v; } ua;
        #pragma unroll
        for (int u = 0; u < 8; ++u)
          ua.h[u] = klds[buf][kk * 32 + quad * 8 + u][w * 32 + it * 16 + m];
        M[it] = MFMA(ua.v, vd, M[it]);
      }
    }

    // k cvt + ds_write into next buffer (loads have had full GEMM cover);
    // drained by next B1.
    #pragma unroll
    for (int g = 0; g < 4; ++g)
      *(bf16x8*)&klds[nbuf][krow][kc4 * 32 + g * 8] =
          cvt8(kpre[2 * g], kpre[2 * g + 1]);
  }
}

extern "C" void kernel_launch(void* const* d_in, const int* in_sizes, int n_in,
                              void* d_out, int out_size, void* d_ws, size_t ws_size,
                              hipStream_t stream) {
  const float* q  = (const float*)d_in[0];
  const float* k  = (const float*)d_in[1];
  const float* v  = (const float*)d_in[2];
  const float* a  = (const float*)d_in[3];
  const float* r  = (const float*)d_in[4];
  const float* l  = (const float*)d_in[5];
  const float* m0 = (const float*)d_in[6];
  float* out = (float*)d_out;

  dim3 grid(NSPLIT, B_);
  lmm_2b<<<grid, 256, 0, stream>>>(q, k, v, a, r, l, m0, out);
}

// Round 6
// 324.005 us; speedup vs baseline: 1.0414x; 1.0414x over previous
//
#include <hip/hip_runtime.h>
#include <hip/hip_bf16.h>

// LatentMatrixMemory: M_t = lam*M + (rho*alpha)*(k outer v); r_t = q^T M_t
// B=64, T=2048, DK=DV=128, fp32 in/out. Threshold permits bf16 compute.
//
// Round 8: keep 2 blocks/CU (r7), remove the three measured chain items.
//  - GEMM4 reads a dedicated transposed tile kT[128][72] bf16 (conflict-free
//    b128) instead of a 32x scalar 8-way-conflicted gather. kT is staged in
//    phase A by transpose-READING the fp32 klds (lanes read consecutive i in
//    a row -> XOR-spread, conflict-free; no extra HBM/L2 traffic).
//  - klds back to fp32 + global_load_lds (r5's source-XOR), SINGLE-buffered:
//    its only readers (GEMM1 + kT staging) run in phase A; the DMA for ch+1
//    issues in phase B (all waves past B2) and drains at B1.
//  - The serial 6-shfl decay scan runs in phase B (overlapped with GEMM3/2/4)
//    on scalars prefetched at top of phase A; results carry in registers.
//  - Sd gets a 16B-block XOR swizzle f(row)=(row>>2)&3: mask writes 4-way->2-way.
//  All shared LDS single-buffered (~68 KB); barriers B1/B2 give separation.
// Grid: 8 DV-splits x 64 batches = 512 blocks; block = 4 waves; 2 blocks/CU.

typedef float  f32x4  __attribute__((ext_vector_type(4)));
typedef short  bf16x8 __attribute__((ext_vector_type(8)));
typedef short  bf16x4 __attribute__((ext_vector_type(4)));

constexpr int B_ = 64, T_ = 2048;
constexpr int NSPLIT = 8;
constexpr int CT = 64;          // chunk length
constexpr int NCH = T_ / CT;    // 32 chunks

__device__ __forceinline__ bf16x8 cvt8(float4 a, float4 b) {
  union { __hip_bfloat162 h2[4]; bf16x8 v; } u;
  u.h2[0] = __float22bfloat162_rn(make_float2(a.x, a.y));
  u.h2[1] = __float22bfloat162_rn(make_float2(a.z, a.w));
  u.h2[2] = __float22bfloat162_rn(make_float2(b.x, b.y));
  u.h2[3] = __float22bfloat162_rn(make_float2(b.z, b.w));
  return u.v;
}

__device__ __forceinline__ float fexp2(float x) { return __builtin_exp2f(x); }
__device__ __forceinline__ float flog2(float x) { return __builtin_log2f(x); }

#define MFMA(a, b, c) __builtin_amdgcn_mfma_f32_16x16x32_bf16((a), (b), (c), 0, 0, 0)

__device__ __forceinline__ void gload16(const float* gsrc, float* ldst) {
  __builtin_amdgcn_global_load_lds(
      (const __attribute__((address_space(1))) void*)gsrc,
      (__attribute__((address_space(3))) void*)ldst, 16, 0, 0);
}

__global__ __launch_bounds__(256, 2) void lmm_v8(
    const float* __restrict__ q_g, const float* __restrict__ k_g,
    const float* __restrict__ v_g, const float* __restrict__ a_g,
    const float* __restrict__ r_g, const float* __restrict__ l_g,
    const float* __restrict__ m0_g, float* __restrict__ out_g)
{
  // XCD-chunked bijective swizzle: all 8 splits of a batch share an XCD.
  const int bid   = blockIdx.y * NSPLIT + blockIdx.x;   // 0..511
  const int b     = (bid & 7) * 8 + (bid >> 6);
  const int split = (bid >> 3) & 7;

  const int tid   = threadIdx.x;
  const int w     = tid >> 6;        // wave 0..3
  const int lane  = tid & 63;
  const int m     = lane & 15;
  const int quad  = lane >> 4;
  const int jbase = split * 16;

  // Single-buffered LDS (~68 KB total -> 2 blocks/CU).
  // klds fp32, 16B-block source-XOR: phys block p of row holds logical p^(row&7).
  __shared__ __align__(16) float klds[64][128];              // 32 KB
  __shared__ __align__(16) __hip_bfloat16 kT [128][72];      // k^T bf16 [i][s]
  __shared__ __align__(16) __hip_bfloat16 MhT[16][136];      // bf16(M)^T [j][i]
  __shared__ __align__(16) __hip_bfloat16 VwT [16][72];      // (ar*v)^T [j][s]
  __shared__ __align__(16) __hip_bfloat16 VwTd[16][72];      // (ar*ratio*v)^T
  __shared__ __align__(16) __hip_bfloat16 Sd[4][16][72];     // scores, block-XOR

  const float* qb = q_g + (size_t)b * T_ * 128;
  const float* kb = k_g + (size_t)b * T_ * 128;
  const float* vb = v_g + (size_t)b * T_ * 128;
  const float* ab = a_g + (size_t)b * T_;
  const float* rb = r_g + (size_t)b * T_;
  const float* lb = l_g + (size_t)b * T_;
  float*       ob = out_g + (size_t)b * T_ * 128;

  // ---- M accumulator: wave w owns i-rows [32w,+32), j-cols [jbase,+16) ----
  f32x4 M[2];
  #pragma unroll
  for (int it = 0; it < 2; ++it)
    #pragma unroll
    for (int r = 0; r < 4; ++r)
      M[it][r] = m0_g[((size_t)b * 128 + w * 32 + it * 16 + quad * 4 + r) * 128 +
                      jbase + m];

  // ---- lane mappings ----
  const int jv   = tid & 15;           // V staging column
  const int s16  = tid >> 4;           // V staging 4-row s-block
  const int prow = lane >> 5;          // k-DMA row parity
  const int pblk = lane & 31;          // k-DMA 16B block
  const int ti   = lane + ((w & 1) << 6);  // kT staging: own i
  const int tsh  = w >> 1;                 // kT staging: s-half
  const int tl0  = w * 16 + quad * 4;      // own t-rows base

  float4 qpre[4][2];
  float  vpre[4];
  float  lpre, apre, rpre;
  float  L2c, L2ec, tlc[4], arpc;      // carried decay state (current chunk)

  // ---- prologue: stage chunk 0, scan chunk 0 (exposed once) ----
  lpre = lb[lane]; apre = ab[lane]; rpre = rb[lane];
  #pragma unroll
  for (int c = 0; c < 8; ++c) {        // wave w stages k rows [16w,16w+16)
    const int row = w * 16 + c * 2 + prow;
    gload16(kb + (size_t)row * 128 + ((pblk ^ (row & 7)) << 2),
            &klds[w * 16 + c * 2][0]);
  }
  #pragma unroll
  for (int ks = 0; ks < 4; ++ks) {
    const float* p = qb + (size_t)(w * 16 + m) * 128 + ks * 32 + quad * 8;
    qpre[ks][0] = *(const float4*)p;
    qpre[ks][1] = *(const float4*)(p + 4);
  }
  #pragma unroll
  for (int rep = 0; rep < 4; ++rep)
    vpre[rep] = vb[(size_t)(s16 * 4 + rep) * 128 + jbase + jv];
  {
    float x = flog2(fmaxf(lpre, 1e-20f));
    #pragma unroll
    for (int d = 1; d < 64; d <<= 1) {
      const float o = __shfl_up(x, d, 64);
      if (lane >= d) x += o;
    }
    L2c = x; L2ec = __shfl(L2c, 63, 64);
    #pragma unroll
    for (int r = 0; r < 4; ++r) tlc[r] = __shfl(L2c, tl0 + r, 64);
    arpc = apre * rpre;
  }

  #pragma unroll 1
  for (int ch = 0; ch < NCH; ++ch) {
    const int t0 = ch * CT;
    const int tn = (ch + 1 < NCH) ? t0 + CT : t0;   // clamped prefetch base

    __syncthreads();  // B1: klds/q/v(ch) valid; WAR on all staged LDS

    // ================= phase A =================
    // scalars for ch+1 (drained free at B2, scanned in phase B)
    lpre = lb[tn + lane]; apre = ab[tn + lane]; rpre = rb[tn + lane];

    // kT staging: transpose-read fp32 klds (conflict-free: lanes read
    // consecutive i within a row, XOR spreads blocks), cvt, b128 write.
    #pragma unroll
    for (int g = 0; g < 4; ++g) {
      float kc[8];
      #pragma unroll
      for (int u2 = 0; u2 < 8; ++u2) {
        const int row = tsh * 32 + g * 8 + u2;
        kc[u2] = klds[row][((((ti >> 2) ^ (row & 7)) << 2) | (ti & 3))];
      }
      *(bf16x8*)&kT[ti][tsh * 32 + g * 8] =
          cvt8(make_float4(kc[0], kc[1], kc[2], kc[3]),
               make_float4(kc[4], kc[5], kc[6], kc[7]));
    }

    bf16x8 qf[4];
    #pragma unroll
    for (int ks = 0; ks < 4; ++ks) qf[ks] = cvt8(qpre[ks][0], qpre[ks][1]);

    // GEMM1: own 16 t-rows x all 64 s, k fp32 from swizzled klds
    f32x4 S[4] = {{0.f,0.f,0.f,0.f},{0.f,0.f,0.f,0.f},
                  {0.f,0.f,0.f,0.f},{0.f,0.f,0.f,0.f}};
    #pragma unroll
    for (int sb = 0; sb < 4; ++sb) {
      const int rowk = sb * 16 + m;
      const int xk   = rowk & 7;
      #pragma unroll
      for (int ks = 0; ks < 4; ++ks) {
        const int bk0 = ks * 8 + quad * 2;
        const float4 kA = *(const float4*)&klds[rowk][((bk0      ^ xk) << 2)];
        const float4 kB = *(const float4*)&klds[rowk][(((bk0 + 1) ^ xk) << 2)];
        S[sb] = MFMA(qf[ks], cvt8(kA, kB), S[sb]);
      }
    }

    // decay + causal mask -> Sd (16B-block XOR f(row)=(row>>2)&3; write rows
    // quad*4+r -> f=quad; 2-way instead of 4-way)
    #pragma unroll
    for (int sb = 0; sb < 4; ++sb) {
      const int   sl_i = sb * 16 + m;
      const float sl   = __shfl(L2c, sl_i, 64);
      #pragma unroll
      for (int r = 0; r < 4; ++r) {
        const float dv = (sl_i <= tl0 + r) ? S[sb][r] * fexp2(tlc[r] - sl) : 0.f;
        Sd[w][quad * 4 + r][((((sl_i >> 3) ^ quad) << 3) | (sl_i & 7))] =
            __float2bfloat16(dv);
      }
    }

    // stage VwT = (ar*v)^T and VwTd = (ar*ratio*v)^T
    {
      float fw[4], fd[4];
      #pragma unroll
      for (int rep = 0; rep < 4; ++rep) {
        const int   s   = s16 * 4 + rep;
        const float arf = __shfl(arpc, s, 64);
        const float dcf = fexp2(L2ec - __shfl(L2c, s, 64));   // <= 1
        fw[rep] = vpre[rep] * arf;
        fd[rep] = fw[rep] * dcf;
      }
      union { __hip_bfloat162 h2[2]; bf16x4 v; } uw, ud;
      uw.h2[0] = __float22bfloat162_rn(make_float2(fw[0], fw[1]));
      uw.h2[1] = __float22bfloat162_rn(make_float2(fw[2], fw[3]));
      ud.h2[0] = __float22bfloat162_rn(make_float2(fd[0], fd[1]));
      ud.h2[1] = __float22bfloat162_rn(make_float2(fd[2], fd[3]));
      *(bf16x4*)&VwT [jv][s16 * 4] = uw.v;
      *(bf16x4*)&VwTd[jv][s16 * 4] = ud.v;
    }

    // publish bf16(M)^T (state at chunk start)
    #pragma unroll
    for (int it = 0; it < 2; ++it) {
      union { __hip_bfloat162 h2[2]; uint2 u; } pk;
      pk.h2[0] = __float22bfloat162_rn(make_float2(M[it][0], M[it][1]));
      pk.h2[1] = __float22bfloat162_rn(make_float2(M[it][2], M[it][3]));
      *(uint2*)&MhT[m][w * 32 + it * 16 + quad * 4] = pk.u;
    }

    __syncthreads();  // B2: kT/Sd/VwT/VwTd/MhT visible; scalars(ch+1) drained

    // ================= phase B =================
    // stage ch+1: klds DMA (readers of klds(ch) all finished before B2) +
    // q/v register prefetch. Drained at next B1.
    #pragma unroll
    for (int c = 0; c < 8; ++c) {
      const int row = w * 16 + c * 2 + prow;
      gload16(kb + (size_t)(tn + row) * 128 + ((pblk ^ (row & 7)) << 2),
              &klds[w * 16 + c * 2][0]);
    }
    #pragma unroll
    for (int ks = 0; ks < 4; ++ks) {
      const float* p = qb + (size_t)(tn + w * 16 + m) * 128 + ks * 32 + quad * 8;
      qpre[ks][0] = *(const float4*)p;
      qpre[ks][1] = *(const float4*)(p + 4);
    }
    #pragma unroll
    for (int rep = 0; rep < 4; ++rep)
      vpre[rep] = vb[(size_t)(tn + s16 * 4 + rep) * 128 + jbase + jv];

    // GEMM3: inter-chunk readout q . bf16(M)
    f32x4 R = {0.f, 0.f, 0.f, 0.f};
    #pragma unroll
    for (int ks = 0; ks < 4; ++ks) {
      const bf16x8 mb = *(const bf16x8*)&MhT[m][ks * 32 + quad * 8];
      R = MFMA(qf[ks], mb, R);
    }
    #pragma unroll
    for (int r = 0; r < 4; ++r) R[r] *= fexp2(tlc[r]);   // P_t <= 1

    // GEMM2: intra-chunk (decay folded into Sd; block-XOR read f=(m>>2)&3)
    #pragma unroll
    for (int kk = 0; kk < 2; ++kk) {
      const bf16x8 sa = *(const bf16x8*)
          &Sd[w][m][(((kk * 4 + quad) ^ ((m >> 2) & 3)) << 3)];
      const bf16x8 vw = *(const bf16x8*)&VwT[m][kk * 32 + quad * 8];
      R = MFMA(sa, vw, R);
    }
    #pragma unroll
    for (int r = 0; r < 4; ++r)
      ob[(size_t)(t0 + w * 16 + quad * 4 + r) * 128 + jbase + m] = R[r];

    // GEMM4: M = exp2(L2_end)*M + K^T (ar*ratio*v); kT b128, conflict-free
    const float eend = fexp2(L2ec);
    #pragma unroll
    for (int it = 0; it < 2; ++it)
      #pragma unroll
      for (int r = 0; r < 4; ++r) M[it][r] *= eend;
    #pragma unroll
    for (int kk = 0; kk < 2; ++kk) {
      const bf16x8 vd = *(const bf16x8*)&VwTd[m][kk * 32 + quad * 8];
      #pragma unroll
      for (int it = 0; it < 2; ++it) {
        const bf16x8 af =
            *(const bf16x8*)&kT[w * 32 + it * 16 + m][kk * 32 + quad * 8];
        M[it] = MFMA(af, vd, M[it]);
      }
    }

    // scan for ch+1 (overlaps GEMMs above; scalars already drained at B2)
    {
      float x = flog2(fmaxf(lpre, 1e-20f));
      #pragma unroll
      for (int d = 1; d < 64; d <<= 1) {
        const float o = __shfl_up(x, d, 64);
        if (lane >= d) x += o;
      }
      L2c = x; L2ec = __shfl(L2c, 63, 64);
      #pragma unroll
      for (int r = 0; r < 4; ++r) tlc[r] = __shfl(L2c, tl0 + r, 64);
      arpc = apre * rpre;
    }
  }
}

extern "C" void kernel_launch(void* const* d_in, const int* in_sizes, int n_in,
                              void* d_out, int out_size, void* d_ws, size_t ws_size,
                              hipStream_t stream) {
  const float* q  = (const float*)d_in[0];
  const float* k  = (const float*)d_in[1];
  const float* v  = (const float*)d_in[2];
  const float* a  = (const float*)d_in[3];
  const float* r  = (const float*)d_in[4];
  const float* l  = (const float*)d_in[5];
  const float* m0 = (const float*)d_in[6];
  float* out = (float*)d_out;

  dim3 grid(NSPLIT, B_);
  lmm_v8<<<grid, 256, 0, stream>>>(q, k, v, a, r, l, m0, out);
}